// Round 5
// baseline (80.473 us; speedup 1.0000x reference)
//
#include <hip/hip_runtime.h>

// Conv2d 7x7 s2 p3, 1ch, 8192^2 fp32 -> 4096^2 fp32.
// Persistent column blocks: 64-wide x 256-tall output strip per 256-thread
// block, 16 steps x 16 output rows. Input rows in a 69-row LDS ring
// (36.7KB -> 4 blocks/CU). Per step: issue next 32 input rows -> regs
// (T14 issue-early), compute current step from ring, ds_write prefetch
// (vmcnt drains here, hidden under compute), one barrier. Ring slot
// aliasing proof in round-5 notes: writes touch only rows >= 2 steps dead.
// XOR-swizzled LDS chunks (write & read side; global linear) => <=2-way banks.

#define THREADS 256
#define STEP 16            // output rows per step
#define NSTEPS 16          // 256 output rows per block
#define RING 69            // ring capacity in input rows (37 live + 32 prefetch)
#define CHUNKS 34          // float4 chunks per input row (136 cols, aligned)
#define ROWF (CHUNKS * 4)  // floats per LDS row
#define IMG 8192
#define OUTW 4096
#define PRO_CHUNKS (37 * CHUNKS)  // 1258 (prologue: rows u=0..36)
#define PRE_CHUNKS (32 * CHUNKS)  // 1088 (per-step prefetch: 32 rows)

__global__ __launch_bounds__(THREADS, 4)
void conv7x7_s2(const float* __restrict__ x, const float* __restrict__ wgt,
                const float* __restrict__ bias, float* __restrict__ out) {
  __shared__ __align__(16) float lds[RING * ROWF];
  const int t = threadIdx.x;
  const int bx = blockIdx.x, by = blockIdx.y;
  const int g0c4 = bx * 128 - 4;   // aligned global col of chunk 0
  const int grow0 = by * 512 - 3;  // global row of local input row u=0

  float wv[49];
#pragma unroll
  for (int i = 0; i < 49; ++i) wv[i] = wgt[i];  // uniform -> s_load/SGPR
  const float bv = bias[0];

  // staging decomposition: round i handles chunk c = t + 256*i of a batch
  int s_dr[5], s_q[5];
#pragma unroll
  for (int i = 0; i < 5; ++i) {
    const int c = t + THREADS * i;
    s_dr[i] = c / CHUNKS;            // row within batch (magic-mul div)
    s_q[i] = c - s_dr[i] * CHUNKS;   // chunk within row
  }

  // ---- prologue: stage rows u=0..36 (slots 0..36), linear global reads ----
  {
    float4 v[5];
#pragma unroll
    for (int i = 0; i < 5; ++i) {
      const int c = t + THREADS * i;
      const int gr = grow0 + s_dr[i];
      const int gc = g0c4 + 4 * s_q[i];
      v[i] = make_float4(0.f, 0.f, 0.f, 0.f);
      if (c < PRO_CHUNKS && (unsigned)gr < (unsigned)IMG &&
          (unsigned)gc < (unsigned)(IMG - 3))
        v[i] = *reinterpret_cast<const float4*>(&x[(long long)gr * IMG + gc]);
    }
#pragma unroll
    for (int i = 0; i < 5; ++i) {
      const int c = t + THREADS * i;
      if (c < PRO_CHUNKS) {
        const int s = s_dr[i];               // slot = u (u<37, no wrap)
        const int xs = (s >> 2) & 7;
        const int q = s_q[i];
        const int lq = (q < 32) ? (q ^ xs) : q;
        *reinterpret_cast<float4*>(&lds[s * ROWF + lq * 4]) = v[i];
      }
    }
  }
  __syncthreads();

  const int tx = t & 15;    // 4-wide output group
  const int ty = t >> 4;    // 0..15, one output row per thread per step
  int sbase = 0;            // slot of input row u = 32k  (32k mod 69)

  for (int k = 0; k < NSTEPS; ++k) {
    // ---- A: issue prefetch for next step (rows u = 32k+37 .. 32k+68) ----
    float4 pf[5];
    if (k != NSTEPS - 1) {
#pragma unroll
      for (int i = 0; i < 5; ++i) {
        const int c = t + THREADS * i;
        const int gr = grow0 + 32 * k + 37 + s_dr[i];
        const int gc = g0c4 + 4 * s_q[i];
        pf[i] = make_float4(0.f, 0.f, 0.f, 0.f);
        if (c < PRE_CHUNKS && (unsigned)gr < (unsigned)IMG &&
            (unsigned)gc < (unsigned)(IMG - 3))
          pf[i] = *reinterpret_cast<const float4*>(&x[(long long)gr * IMG + gc]);
      }
    }

    // ---- B: compute 4 outputs from ring (rows u = 32k+2ty .. +2ty+6) ----
    float acc[4] = {bv, bv, bv, bv};
#pragma unroll
    for (int kh = 0; kh < 7; ++kh) {
      int sl = sbase + 2 * ty + kh;
      if (sl >= RING) sl -= RING;
      const int xr = (sl >> 2) & 7;
      float rb[16];
#pragma unroll
      for (int q2 = 0; q2 < 4; ++q2) {
        const int cch = 2 * tx + q2;
        const int lq = (cch < 32) ? (cch ^ xr) : cch;
        const float4 vv =
            *reinterpret_cast<const float4*>(&lds[sl * ROWF + lq * 4]);
        rb[4 * q2 + 0] = vv.x;
        rb[4 * q2 + 1] = vv.y;
        rb[4 * q2 + 2] = vv.z;
        rb[4 * q2 + 3] = vv.w;
      }
      // rb[i] = input col (8tx+i) rel. to g0c4; out col 4tx+xx needs 8tx+2xx+kw+1
#pragma unroll
      for (int xx = 0; xx < 4; ++xx)
#pragma unroll
        for (int kw = 0; kw < 7; ++kw)
          acc[xx] = fmaf(rb[2 * xx + kw + 1], wv[7 * kh + kw], acc[xx]);
    }
    const int oy = by * 256 + 16 * k + ty;
    *reinterpret_cast<float4*>(&out[(long long)oy * OUTW + bx * 64 + 4 * tx]) =
        make_float4(acc[0], acc[1], acc[2], acc[3]);

    // ---- C: ds_write prefetch (vmcnt waits here, hidden under B) ----
    if (k != NSTEPS - 1) {
#pragma unroll
      for (int i = 0; i < 5; ++i) {
        const int c = t + THREADS * i;
        if (c < PRE_CHUNKS) {
          int s = sbase + 37 + s_dr[i];     // (u mod 69); max 136 < 2*69
          if (s >= RING) s -= RING;
          if (s >= RING) s -= RING;
          const int xs = (s >> 2) & 7;
          const int q = s_q[i];
          const int lq = (q < 32) ? (q ^ xs) : q;
          *reinterpret_cast<float4*>(&lds[s * ROWF + lq * 4]) = pf[i];
        }
      }
    }
    __syncthreads();
    sbase += 32;
    if (sbase >= RING) sbase -= RING;
  }
}

extern "C" void kernel_launch(void* const* d_in, const int* in_sizes, int n_in,
                              void* d_out, int out_size, void* d_ws, size_t ws_size,
                              hipStream_t stream) {
  const float* x = (const float*)d_in[0];
  const float* w = (const float*)d_in[1];
  const float* b = (const float*)d_in[2];
  float* out = (float*)d_out;
  dim3 grid(OUTW / 64, 16);  // 64 x 16 = 1024 blocks = 4/CU
  conv7x7_s2<<<grid, dim3(THREADS), 0, stream>>>(x, w, b, out);
}

// Round 6
// 66.999 us; speedup vs baseline: 1.2011x; 1.2011x over previous
//
#include <hip/hip_runtime.h>

// Conv2d 7x7 s2 p3, 1ch, 8192^2 fp32 -> 4096^2 fp32.
// 128x16 output tile / 256-thread block, 4x2 outputs per thread.
// Row segments now 1056B contiguous (2x wider than before) for DRAM page
// locality. LDS 40KB (37 rows x 66 chunks, linear in slot) -> 4 blocks/CU.
// Interior: async global_load_lds(16B), swizzle via pre-swizzled global src.
// Edges: reg staging with bounds checks. Read: XOR-swizzled ds_read_b128.

#define THREADS 256
#define TILE_W 128
#define TILE_H 16
#define IN_H 37            // TILE_H*2 + 5
#define CHUNKS 66          // float4 chunks per LDS row (264 cols, aligned)
#define LDS_STRIDE (CHUNKS * 4)
#define NSLOT (IN_H * CHUNKS)   // 2442
#define NSLOT_PAD 2560          // 10 rounds x 256 threads; 40 KB LDS
#define IMG 8192
#define OUTW 4096

typedef __attribute__((address_space(1))) const void global_cv;
typedef __attribute__((address_space(3))) void lds_v;

__global__ __launch_bounds__(THREADS, 4)
void conv7x7_s2(const float* __restrict__ x, const float* __restrict__ wgt,
                const float* __restrict__ bias, float* __restrict__ out) {
  __shared__ __align__(16) float lds[NSLOT_PAD * 4];
  const int t = threadIdx.x;
  const int tile_x = blockIdx.x * TILE_W;
  const int tile_y = blockIdx.y * TILE_H;
  const int g0c4 = tile_x * 2 - 4;  // aligned input col of LDS chunk 0
  const int g0r = tile_y * 2 - 3;   // input row of LDS row 0

  float wv[49];
#pragma unroll
  for (int i = 0; i < 49; ++i) wv[i] = wgt[i];   // uniform -> SGPRs
  const float bv = bias[0];

  const bool interior = (blockIdx.x >= 1) & (blockIdx.x <= 30) &
                        (blockIdx.y >= 1) & (blockIdx.y <= 254);

  if (interior) {
    // ---- async staging: HBM -> LDS direct, no bounds checks ----
    const float* xb = x + (long long)g0r * IMG + g0c4;
#pragma unroll
    for (int i = 0; i < 10; ++i) {
      const int s = t + THREADS * i;        // linear LDS chunk index
      const int r = s / CHUNKS;
      const int q = s - r * CHUNKS;
      const int xr = (r >> 2) & 7;
      const int src = (q < 64) ? (q ^ xr) : q;  // pre-swizzled global chunk
      const float* gp = xb + r * IMG + 4 * src;
      if (i == 9 && s >= NSLOT) gp = x;     // pad lanes: any valid address
      __builtin_amdgcn_global_load_lds((global_cv*)gp, (lds_v*)&lds[s * 4],
                                       16, 0, 0);
    }
  } else {
    // ---- edge path: register staging with bounds checks ----
    float4 vbuf[10];
    int laddr[10];
#pragma unroll
    for (int i = 0; i < 10; ++i) {
      const int s = t + THREADS * i;
      const bool ok = (s < NSLOT);
      const int r = s / CHUNKS;
      const int q = s - r * CHUNKS;
      const int xr = (r >> 2) & 7;
      const int src = (q < 64) ? (q ^ xr) : q;
      const int gr = g0r + r;
      const int gc = g0c4 + 4 * src;
      float4 v = make_float4(0.f, 0.f, 0.f, 0.f);
      if (ok && (unsigned)gr < (unsigned)IMG && (unsigned)gc < (unsigned)(IMG - 3))
        v = *reinterpret_cast<const float4*>(&x[(long long)gr * IMG + gc]);
      vbuf[i] = v;
      laddr[i] = ok ? s * 4 : -1;
    }
#pragma unroll
    for (int i = 0; i < 10; ++i)
      if (laddr[i] >= 0) *reinterpret_cast<float4*>(&lds[laddr[i]]) = vbuf[i];
  }
  __syncthreads();   // drains vmcnt (global_load_lds) + lgkmcnt

  // ---- compute: 4 wide x 2 tall per thread ----
  const int tx = t & 31;          // 0..31 -> 128 output cols
  const int ty = t >> 5;          // 0..7  -> 2 output rows each
  float acc[2][4];
#pragma unroll
  for (int y = 0; y < 2; ++y)
#pragma unroll
    for (int xx = 0; xx < 4; ++xx) acc[y][xx] = bv;

#pragma unroll
  for (int j = 0; j < 9; ++j) {
    const int sl = 4 * ty + j;    // LDS input row, max 36
    const int xr = (sl >> 2) & 7;
    float rbuf[16];
#pragma unroll
    for (int q = 0; q < 4; ++q) {
      const int c = 2 * tx + q;   // global chunk wanted, max 65
      const int lq = (c < 64) ? (c ^ xr) : c;
      const float4 v =
          *reinterpret_cast<const float4*>(&lds[sl * LDS_STRIDE + lq * 4]);
      rbuf[4 * q + 0] = v.x;
      rbuf[4 * q + 1] = v.y;
      rbuf[4 * q + 2] = v.z;
      rbuf[4 * q + 3] = v.w;
    }
    // rbuf[i] = input col (8tx+i) rel. to g0c4; out col 4tx+xx needs 8tx+2xx+kw+1
#pragma unroll
    for (int y = 0; y < 2; ++y) {
      const int kh = j - 2 * y;
      if (kh >= 0 && kh <= 6) {
#pragma unroll
        for (int xx = 0; xx < 4; ++xx)
#pragma unroll
          for (int kw = 0; kw < 7; ++kw)
            acc[y][xx] = fmaf(rbuf[2 * xx + kw + 1], wv[kh * 7 + kw], acc[y][xx]);
      }
    }
  }

  // ---- store: 2 x global_store_dwordx4, 512B contiguous per wave-row ----
  const int ox = tile_x + 4 * tx;
  const int oy = tile_y + 2 * ty;
#pragma unroll
  for (int y = 0; y < 2; ++y) {
    float4 v = make_float4(acc[y][0], acc[y][1], acc[y][2], acc[y][3]);
    *reinterpret_cast<float4*>(&out[(long long)(oy + y) * OUTW + ox]) = v;
  }
}

extern "C" void kernel_launch(void* const* d_in, const int* in_sizes, int n_in,
                              void* d_out, int out_size, void* d_ws, size_t ws_size,
                              hipStream_t stream) {
  const float* x = (const float*)d_in[0];
  const float* w = (const float*)d_in[1];
  const float* b = (const float*)d_in[2];
  float* out = (float*)d_out;
  dim3 grid(OUTW / TILE_W, OUTW / TILE_H);  // 32 x 256
  conv7x7_s2<<<grid, dim3(THREADS), 0, stream>>>(x, w, b, out);
}

// Round 7
// 65.516 us; speedup vs baseline: 1.2283x; 1.0226x over previous
//
#include <hip/hip_runtime.h>

// Conv2d 7x7 s2 p3, 1ch, 8192^2 fp32 -> 4096^2 fp32.
// 256x8 output tile / 256-thread block, 4x2 outputs per thread.
// Row segments 2080B contiguous (2x round 6) for DRAM page locality.
// LDS: 21 rows x 130 chunks, PARITY-INTERLEAVED per row (even chunks ->
// slots 0..64, odd -> 65..129). Reads are 64 consecutive slots across a
// wave => minimum bank occupancy, no XOR swizzle needed.
// Interior: async global_load_lds(16B) with inverse-map on global source.
// Edges: register staging with bounds checks.

#define THREADS 256
#define TILE_W 256
#define TILE_H 8
#define IN_H 21              // TILE_H*2 + 5
#define CHUNKS 130           // float4 chunks per input row (520 cols)
#define ROWF (CHUNKS * 4)    // floats per LDS row
#define NSLOT (IN_H * CHUNKS)   // 2730
#define NROUND 11               // ceil(2730/256)
#define NSLOT_PAD (NROUND * THREADS)  // 2816 chunks -> 45056 B LDS
#define IMG 8192
#define OUTW 4096

typedef __attribute__((address_space(1))) const void global_cv;
typedef __attribute__((address_space(3))) void lds_v;

__global__ __launch_bounds__(THREADS, 3)
void conv7x7_s2(const float* __restrict__ x, const float* __restrict__ wgt,
                const float* __restrict__ bias, float* __restrict__ out) {
  __shared__ __align__(16) float lds[NSLOT_PAD * 4];
  const int t = threadIdx.x;
  const int tile_x = blockIdx.x * TILE_W;
  const int tile_y = blockIdx.y * TILE_H;
  const int g0c4 = tile_x * 2 - 4;  // aligned input col of chunk 0
  const int g0r = tile_y * 2 - 3;   // input row of LDS row 0

  float wv[49];
#pragma unroll
  for (int i = 0; i < 49; ++i) wv[i] = wgt[i];   // uniform -> SGPRs
  const float bv = bias[0];

  // slot s (within row): holds global chunk src = (s<65) ? 2s : 2(s-65)+1
  const bool interior = (blockIdx.x >= 1) & (blockIdx.x <= 14) &
                        (blockIdx.y >= 1) & (blockIdx.y <= 510);

  if (interior) {
    // ---- async staging: HBM -> LDS direct, no bounds checks ----
    const float* xb = x + (long long)g0r * IMG + g0c4;
#pragma unroll
    for (int i = 0; i < NROUND; ++i) {
      const int s = t + THREADS * i;        // linear LDS chunk index
      const int r = s / CHUNKS;
      const int p = s - r * CHUNKS;         // slot within row
      const int src = (p < 65) ? (2 * p) : (2 * (p - 65) + 1);
      const float* gp = xb + r * IMG + 4 * src;
      if (i == NROUND - 1 && s >= NSLOT) gp = x;  // pad lanes: valid addr
      __builtin_amdgcn_global_load_lds((global_cv*)gp, (lds_v*)&lds[s * 4],
                                       16, 0, 0);
    }
  } else {
    // ---- edge path: register staging with bounds checks ----
    float4 vbuf[NROUND];
    int laddr[NROUND];
#pragma unroll
    for (int i = 0; i < NROUND; ++i) {
      const int s = t + THREADS * i;
      const bool ok = (s < NSLOT);
      const int r = s / CHUNKS;
      const int p = s - r * CHUNKS;
      const int src = (p < 65) ? (2 * p) : (2 * (p - 65) + 1);
      const int gr = g0r + r;
      const int gc = g0c4 + 4 * src;
      float4 v = make_float4(0.f, 0.f, 0.f, 0.f);
      if (ok && (unsigned)gr < (unsigned)IMG && (unsigned)gc < (unsigned)(IMG - 3))
        v = *reinterpret_cast<const float4*>(&x[(long long)gr * IMG + gc]);
      vbuf[i] = v;
      laddr[i] = ok ? s * 4 : -1;
    }
#pragma unroll
    for (int i = 0; i < NROUND; ++i)
      if (laddr[i] >= 0) *reinterpret_cast<float4*>(&lds[laddr[i]]) = vbuf[i];
  }
  __syncthreads();   // drains vmcnt (global_load_lds) + lgkmcnt

  // ---- compute: 4 wide x 2 tall per thread ----
  const int tx = t & 63;          // 0..63 -> 256 output cols
  const int ty = t >> 6;          // 0..3  -> 2 output rows each
  float acc[2][4];
#pragma unroll
  for (int y = 0; y < 2; ++y)
#pragma unroll
    for (int xx = 0; xx < 4; ++xx) acc[y][xx] = bv;

#pragma unroll
  for (int j = 0; j < 9; ++j) {
    const int sl = 4 * ty + j;    // LDS input row, max 20
    const float* rp = &lds[sl * ROWF];
    float rbuf[16];
    // chunks 2tx..2tx+3 -> slots tx, 65+tx, tx+1, 66+tx (consecutive/wave)
    {
      const float4 v0 = *reinterpret_cast<const float4*>(rp + (tx) * 4);
      const float4 v1 = *reinterpret_cast<const float4*>(rp + (65 + tx) * 4);
      const float4 v2 = *reinterpret_cast<const float4*>(rp + (tx + 1) * 4);
      const float4 v3 = *reinterpret_cast<const float4*>(rp + (66 + tx) * 4);
      rbuf[0] = v0.x;  rbuf[1] = v0.y;  rbuf[2] = v0.z;  rbuf[3] = v0.w;
      rbuf[4] = v1.x;  rbuf[5] = v1.y;  rbuf[6] = v1.z;  rbuf[7] = v1.w;
      rbuf[8] = v2.x;  rbuf[9] = v2.y;  rbuf[10] = v2.z; rbuf[11] = v2.w;
      rbuf[12] = v3.x; rbuf[13] = v3.y; rbuf[14] = v3.z; rbuf[15] = v3.w;
    }
    // rbuf[i] = input col (8tx+i) rel. to g0c4; out col 4tx+xx needs 8tx+2xx+kw+1
#pragma unroll
    for (int y = 0; y < 2; ++y) {
      const int kh = j - 2 * y;
      if (kh >= 0 && kh <= 6) {
#pragma unroll
        for (int xx = 0; xx < 4; ++xx)
#pragma unroll
          for (int kw = 0; kw < 7; ++kw)
            acc[y][xx] = fmaf(rbuf[2 * xx + kw + 1], wv[kh * 7 + kw], acc[y][xx]);
      }
    }
  }

  // ---- store: 2 x global_store_dwordx4, 1KB contiguous per wave-row ----
  const int ox = tile_x + 4 * tx;
  const int oy = tile_y + 2 * ty;
#pragma unroll
  for (int y = 0; y < 2; ++y) {
    float4 v = make_float4(acc[y][0], acc[y][1], acc[y][2], acc[y][3]);
    *reinterpret_cast<float4*>(&out[(long long)(oy + y) * OUTW + ox]) = v;
  }
}

extern "C" void kernel_launch(void* const* d_in, const int* in_sizes, int n_in,
                              void* d_out, int out_size, void* d_ws, size_t ws_size,
                              hipStream_t stream) {
  const float* x = (const float*)d_in[0];
  const float* w = (const float*)d_in[1];
  const float* b = (const float*)d_in[2];
  float* out = (float*)d_out;
  dim3 grid(OUTW / TILE_W, OUTW / TILE_H);  // 16 x 512
  conv7x7_s2<<<grid, dim3(THREADS), 0, stream>>>(x, w, b, out);
}

// Round 9
// 64.556 us; speedup vs baseline: 1.2466x; 1.0149x over previous
//
#include <hip/hip_runtime.h>

// Conv2d 7x7 s2 p3, 1ch, 8192^2 fp32 -> 4096^2 fp32.
// 256x8 output tile / 256-thread block, 4x2 outputs per thread.
// LDS: 21 rows x 130 chunks, parity-interleaved (even chunks -> slots 0..64,
// odd -> 65..129); reads are 64 consecutive slots across a wave (conflict-free).
// REGISTER staging with DENSE global reads (consecutive lanes -> consecutive
// chunks, 2080B contiguous per row segment); parity scatter applied on the
// ds_write side (two dense 512B regions/wave => <=2-way, free).
// Output stored nontemporal via ext_vector_type (fix for round-8 compile err).

#define THREADS 256
#define TILE_W 256
#define TILE_H 8
#define IN_H 21              // TILE_H*2 + 5
#define CHUNKS 130           // float4 chunks per input row (520 cols)
#define ROWF (CHUNKS * 4)    // floats per LDS row
#define NSLOT (IN_H * CHUNKS)   // 2730
#define NROUND 11               // ceil(2730/256)
#define NSLOT_PAD (NROUND * THREADS)  // 2816 chunks -> 45056 B LDS
#define IMG 8192
#define OUTW 4096

typedef float __attribute__((ext_vector_type(4))) floatx4;

__global__ __launch_bounds__(THREADS, 3)
void conv7x7_s2(const float* __restrict__ x, const float* __restrict__ wgt,
                const float* __restrict__ bias, float* __restrict__ out) {
  __shared__ __align__(16) float lds[NSLOT_PAD * 4];
  const int t = threadIdx.x;
  const int tile_x = blockIdx.x * TILE_W;
  const int tile_y = blockIdx.y * TILE_H;
  const int g0c4 = tile_x * 2 - 4;  // aligned input col of chunk 0
  const int g0r = tile_y * 2 - 3;   // input row of LDS row 0

  float wv[49];
#pragma unroll
  for (int i = 0; i < 49; ++i) wv[i] = wgt[i];   // uniform -> SGPRs
  const float bv = bias[0];

  const bool interior = (blockIdx.x >= 1) & (blockIdx.x <= 14) &
                        (blockIdx.y >= 1) & (blockIdx.y <= 510);

  // ---- staging: dense global loads -> regs, parity-scattered ds_writes ----
  float4 vbuf[NROUND];
  if (interior) {
    const float* xb = x + (long long)g0r * IMG + g0c4;
#pragma unroll
    for (int i = 0; i < NROUND; ++i) {
      const int s = t + THREADS * i;      // dense: lane-consecutive chunks
      if (s < NSLOT) {
        const int r = s / CHUNKS;          // magic-mul div
        const int g = s - r * CHUNKS;      // global chunk within row
        vbuf[i] = *reinterpret_cast<const float4*>(xb + (long long)r * IMG + 4 * g);
      }
    }
  } else {
#pragma unroll
    for (int i = 0; i < NROUND; ++i) {
      const int s = t + THREADS * i;
      const int r = s / CHUNKS;
      const int g = s - r * CHUNKS;
      const int gr = g0r + r;
      const int gc = g0c4 + 4 * g;
      float4 v = make_float4(0.f, 0.f, 0.f, 0.f);
      if (s < NSLOT && (unsigned)gr < (unsigned)IMG &&
          (unsigned)gc < (unsigned)(IMG - 3))
        v = *reinterpret_cast<const float4*>(&x[(long long)gr * IMG + gc]);
      vbuf[i] = v;
    }
  }
#pragma unroll
  for (int i = 0; i < NROUND; ++i) {
    const int s = t + THREADS * i;
    if (s < NSLOT) {
      const int r = s / CHUNKS;
      const int g = s - r * CHUNKS;
      const int sl = (g & 1) ? (65 + (g >> 1)) : (g >> 1);  // parity slot
      *reinterpret_cast<float4*>(&lds[(r * CHUNKS + sl) * 4]) = vbuf[i];
    }
  }
  __syncthreads();

  // ---- compute: 4 wide x 2 tall per thread ----
  const int tx = t & 63;          // 0..63 -> 256 output cols
  const int ty = t >> 6;          // 0..3  -> 2 output rows each
  float acc[2][4];
#pragma unroll
  for (int y = 0; y < 2; ++y)
#pragma unroll
    for (int xx = 0; xx < 4; ++xx) acc[y][xx] = bv;

#pragma unroll
  for (int j = 0; j < 9; ++j) {
    const int sl = 4 * ty + j;    // LDS input row, max 20
    const float* rp = &lds[sl * ROWF];
    float rbuf[16];
    // chunks 2tx..2tx+3 -> slots tx, 65+tx, tx+1, 66+tx (dense across wave)
    {
      const float4 v0 = *reinterpret_cast<const float4*>(rp + (tx) * 4);
      const float4 v1 = *reinterpret_cast<const float4*>(rp + (65 + tx) * 4);
      const float4 v2 = *reinterpret_cast<const float4*>(rp + (tx + 1) * 4);
      const float4 v3 = *reinterpret_cast<const float4*>(rp + (66 + tx) * 4);
      rbuf[0] = v0.x;  rbuf[1] = v0.y;  rbuf[2] = v0.z;  rbuf[3] = v0.w;
      rbuf[4] = v1.x;  rbuf[5] = v1.y;  rbuf[6] = v1.z;  rbuf[7] = v1.w;
      rbuf[8] = v2.x;  rbuf[9] = v2.y;  rbuf[10] = v2.z; rbuf[11] = v2.w;
      rbuf[12] = v3.x; rbuf[13] = v3.y; rbuf[14] = v3.z; rbuf[15] = v3.w;
    }
    // rbuf[i] = input col (8tx+i) rel. to g0c4; out col 4tx+xx needs 8tx+2xx+kw+1
#pragma unroll
    for (int y = 0; y < 2; ++y) {
      const int kh = j - 2 * y;
      if (kh >= 0 && kh <= 6) {
#pragma unroll
        for (int xx = 0; xx < 4; ++xx)
#pragma unroll
          for (int kw = 0; kw < 7; ++kw)
            acc[y][xx] = fmaf(rbuf[2 * xx + kw + 1], wv[kh * 7 + kw], acc[y][xx]);
      }
    }
  }

  // ---- store: nontemporal, 1KB contiguous per wave-row ----
  const int ox = tile_x + 4 * tx;
  const int oy = tile_y + 2 * ty;
#pragma unroll
  for (int y = 0; y < 2; ++y) {
    floatx4 v;
    v.x = acc[y][0]; v.y = acc[y][1]; v.z = acc[y][2]; v.w = acc[y][3];
    __builtin_nontemporal_store(
        v, reinterpret_cast<floatx4*>(&out[(long long)(oy + y) * OUTW + ox]));
  }
}

extern "C" void kernel_launch(void* const* d_in, const int* in_sizes, int n_in,
                              void* d_out, int out_size, void* d_ws, size_t ws_size,
                              hipStream_t stream) {
  const float* x = (const float*)d_in[0];
  const float* w = (const float*)d_in[1];
  const float* b = (const float*)d_in[2];
  float* out = (float*)d_out;
  dim3 grid(OUTW / TILE_W, OUTW / TILE_H);  // 16 x 512
  conv7x7_s2<<<grid, dim3(THREADS), 0, stream>>>(x, w, b, out);
}